// Round 5
// baseline (869.905 us; speedup 1.0000x reference)
//
#include <hip/hip_runtime.h>
#include <cstdint>

typedef __attribute__((ext_vector_type(8))) short short8;
typedef __attribute__((ext_vector_type(4))) float f32x4;

__device__ __forceinline__ unsigned short f2bf(float f) {
    uint32_t u = __builtin_bit_cast(uint32_t, f);
    u += 0x7FFFu + ((u >> 16) & 1u);   // round-to-nearest-even
    return (unsigned short)(u >> 16);
}

// out float offsets: Gii 0, Gti 16384, gt 67125248, obj 67649536
// fp32 scratch lives INSIDE the Gti region (overwritten later by main):
#define SG_OFF   16384     // G fp32 [128][128]
#define SM1_OFF  32768     // M1 = Kii^-1
#define SY_OFF   49152     // Y = G*M1
#define SX_OFF   65536     // X = Lunit^-1 (unit lower, upper zeros)
#define SD_OFF   81920     // d[0..127], [128]=logdetK, [129]=logdetG, [132+bid]=trace partials
// ws bytes [0,32768) = Wt bf16 swizzled; [32768,65536) = Qt bf16 swizzled
// swizzle: byte = (c*256 + k*2) ^ ((c&7)<<4)

// ---------------------------------------------------------------------------
// k0: G = V V^T /128 * e^s  -> out[0..16K) (Gii) and scratch sG. 16 blocks.
// ---------------------------------------------------------------------------
__global__ __launch_bounds__(256) void k0_G(
    const float* __restrict__ V, const float* __restrict__ gs,
    float* __restrict__ out)
{
    float* sG = out + SG_OFF;
    const float egs = expf(gs[0]) * (1.0f / 128.0f);
    const int ty = threadIdx.x >> 5, tx = threadIdx.x & 31;
    const int r = blockIdx.x * 8 + ty;
    const f32x4* V4 = (const f32x4*)V;
    f32x4 acc = {0.f, 0.f, 0.f, 0.f};
    for (int kq = 0; kq < 32; ++kq) {
        const f32x4 vr = V4[r * 32 + kq];
        #pragma unroll
        for (int e = 0; e < 4; ++e) {
            const f32x4 vc = V4[(tx * 4 + e) * 32 + kq];
            acc[e] += vr[0]*vc[0] + vr[1]*vc[1] + vr[2]*vc[2] + vr[3]*vc[3];
        }
    }
    acc *= egs;
    *(f32x4*)&out[r * 128 + tx * 4] = acc;
    *(f32x4*)&sG[r * 128 + tx * 4] = acc;
}

// ---------------------------------------------------------------------------
// k1: register-resident fused dual-LDL^T (K and G) + Gauss-Jordan X = L^-1.
// ---------------------------------------------------------------------------
__global__ __launch_bounds__(512) void k1_factor(
    const float* __restrict__ Kii, float* __restrict__ out)
{
    __shared__ float colA[2][128], colB[2][128], rowX[2][128];
    __shared__ float sDk[128], sDg[128], sRed[4];

    const int tid = threadIdx.x;
    const int ty = tid >> 5, tx = tid & 31;
    const int I0 = ty * 8, J0 = tx * 4;
    const float* sG = out + SG_OFF;
    float* sX = out + SX_OFF;
    float* dbuf = out + SD_OFF;

    f32x4 rA[8], rB[8], rX[8];
    #pragma unroll
    for (int r = 0; r < 8; ++r) {
        rA[r] = *(const f32x4*)&Kii[(size_t)(I0 + r) * 128 + J0];
        rB[r] = *(const f32x4*)&sG[(I0 + r) * 128 + J0];
        f32x4 z = {0.f, 0.f, 0.f, 0.f};
        #pragma unroll
        for (int e = 0; e < 4; ++e) z[e] = (I0 + r == J0 + e) ? 1.0f : 0.0f;
        rX[r] = z;
    }
    if (tx == 0) {
        #pragma unroll
        for (int r = 0; r < 8; ++r) { colA[0][I0 + r] = rA[r][0]; colB[0][I0 + r] = rB[r][0]; }
    }
    if (ty == 0) {
        #pragma unroll
        for (int e = 0; e < 4; ++e) rowX[0][J0 + e] = rX[0][e];
    }
    __syncthreads();

    for (int k = 0; k < 127; ++k) {
        const int b = k & 1;
        const float dK = colA[b][k], dG = colB[b][k];
        const float rdK = 1.0f / dK, rdG = 1.0f / dG;
        if (tid == 0) { sDk[k] = dK; sDg[k] = dG; }

        f32x4 caj = *(const f32x4*)&colA[b][J0];
        f32x4 cbj = *(const f32x4*)&colB[b][J0];
        const f32x4 xj = *(const f32x4*)&rowX[b][J0];
        #pragma unroll
        for (int e = 0; e < 4; ++e)
            if (J0 + e <= k) { caj[e] = 0.0f; cbj[e] = 0.0f; }

        f32x4 ca0 = *(const f32x4*)&colA[b][I0];
        f32x4 ca1 = *(const f32x4*)&colA[b][I0 + 4];
        f32x4 cb0 = *(const f32x4*)&colB[b][I0];
        f32x4 cb1 = *(const f32x4*)&colB[b][I0 + 4];
        #pragma unroll
        for (int r = 0; r < 4; ++r) {
            if (I0 + r <= k)     { ca0[r] = 0.0f; cb0[r] = 0.0f; }
            if (I0 + 4 + r <= k) { ca1[r] = 0.0f; cb1[r] = 0.0f; }
        }

        if (I0 + 7 > k) {
            #pragma unroll
            for (int r = 0; r < 8; ++r) {
                const float am = (r < 4) ? ca0[r & 3] : ca1[r & 3];
                const float bm = (r < 4) ? cb0[r & 3] : cb1[r & 3];
                const float fA = am * rdK;
                const float fB = bm * rdG;
                rA[r] -= fA * caj;
                rB[r] -= fB * cbj;
                rX[r] -= fA * xj;
            }
        }

        const int kn = k + 1, bn = kn & 1;
        if (tx == (kn >> 2)) {
            const int es = kn & 3;
            #pragma unroll
            for (int ee = 0; ee < 4; ++ee) if (ee == es) {
                #pragma unroll
                for (int r = 0; r < 8; ++r) {
                    colA[bn][I0 + r] = rA[r][ee];
                    colB[bn][I0 + r] = rB[r][ee];
                }
            }
        }
        if (ty == (kn >> 3)) {
            const int rs = kn & 7;
            #pragma unroll
            for (int rr = 0; rr < 8; ++rr) if (rr == rs) {
                #pragma unroll
                for (int e = 0; e < 4; ++e) rowX[bn][J0 + e] = rX[rr][e];
            }
        }
        __syncthreads();
    }
    if (tid == 511) { sDk[127] = rA[7][3]; sDg[127] = rB[7][3]; }

    #pragma unroll
    for (int r = 0; r < 8; ++r)
        *(f32x4*)&sX[(I0 + r) * 128 + J0] = rX[r];
    __syncthreads();

    if (tid < 128) {
        dbuf[tid] = sDk[tid];
        float lk = logf(sDk[tid]);
        float lg = logf(sDg[tid]);
        #pragma unroll
        for (int o = 32; o > 0; o >>= 1) { lk += __shfl_xor(lk, o, 64); lg += __shfl_xor(lg, o, 64); }
        if ((tid & 63) == 0) { sRed[(tid >> 6) * 2] = lk; sRed[(tid >> 6) * 2 + 1] = lg; }
    }
    __syncthreads();
    if (tid == 0) {
        dbuf[128] = sRed[0] + sRed[2];   // logdet K
        dbuf[129] = sRed[1] + sRed[3];   // logdet G
    }
}

// ---------------------------------------------------------------------------
// k2: M1 = X^T D^-1 X  (= Kii^-1). 16 blocks.
// ---------------------------------------------------------------------------
__global__ __launch_bounds__(256) void k2_M1(float* __restrict__ out)
{
    const float* sX = out + SX_OFF;
    const float* dbuf = out + SD_OFF;
    float* sM1 = out + SM1_OFF;
    __shared__ float srd[128];
    const int tid = threadIdx.x;
    if (tid < 128) srd[tid] = 1.0f / dbuf[tid];
    __syncthreads();
    const int ty = tid >> 5, tx = tid & 31;
    const int a = blockIdx.x * 8 + ty;
    const f32x4* X4 = (const f32x4*)sX;
    f32x4 acc = {0.f, 0.f, 0.f, 0.f};
    for (int k = a; k < 128; ++k) {          // X[k][a]=0 for k<a
        const float xa = sX[k * 128 + a] * srd[k];
        acc += xa * X4[k * 32 + tx];
    }
    *(f32x4*)&sM1[a * 128 + tx * 4] = acc;
}

// ---------------------------------------------------------------------------
// k3: Y = G*M1 -> scratch + Wt bf16 swizzled; trace partials. 16 blocks.
// ---------------------------------------------------------------------------
__global__ __launch_bounds__(256) void k3_Y(float* __restrict__ out, char* __restrict__ wsb)
{
    const float* sG = out + SG_OFF;
    const float* sM1 = out + SM1_OFF;
    float* sY = out + SY_OFF;
    float* dbuf = out + SD_OFF;
    const int tid = threadIdx.x;
    const int ty = tid >> 5, tx = tid & 31;
    const int c = blockIdx.x * 8 + ty;
    const f32x4* M14 = (const f32x4*)sM1;
    f32x4 acc = {0.f, 0.f, 0.f, 0.f};
    for (int m = 0; m < 128; ++m)
        acc += sG[c * 128 + m] * M14[m * 32 + tx];
    *(f32x4*)&sY[c * 128 + tx * 4] = acc;
    const uint32_t lo = (uint32_t)f2bf(acc[0]) | ((uint32_t)f2bf(acc[1]) << 16);
    const uint32_t hi = (uint32_t)f2bf(acc[2]) | ((uint32_t)f2bf(acc[3]) << 16);
    const uint32_t byteoff = (uint32_t)((c * 256 + tx * 8) ^ ((c & 7) << 4));
    *(uint2*)(wsb + byteoff) = make_uint2(lo, hi);
    float t;
    {
        const f32x4* G4 = (const f32x4*)sG;
        const int idx = blockIdx.x * 256 + tid;
        const f32x4 g = G4[idx], mm = M14[idx];
        t = g[0]*mm[0] + g[1]*mm[1] + g[2]*mm[2] + g[3]*mm[3];
    }
    #pragma unroll
    for (int o = 32; o > 0; o >>= 1) t += __shfl_xor(t, o, 64);
    __shared__ float sp[4];
    if ((tid & 63) == 0) sp[tid >> 6] = t;
    __syncthreads();
    if (tid == 0) dbuf[132 + blockIdx.x] = sp[0] + sp[1] + sp[2] + sp[3];
}

// ---------------------------------------------------------------------------
// k4: Q = M1*Y - M1 -> Qt bf16 swizzled; finalize obj. 16 blocks.
// ---------------------------------------------------------------------------
__global__ __launch_bounds__(256) void k4_Q(
    float* __restrict__ out, char* __restrict__ wsb, const int* __restrict__ dofp)
{
    const float* sM1 = out + SM1_OFF;
    const float* sY = out + SY_OFF;
    const float* dbuf = out + SD_OFF;
    const int tid = threadIdx.x;
    const int ty = tid >> 5, tx = tid & 31;
    const int c = blockIdx.x * 8 + ty;
    const f32x4* Y4 = (const f32x4*)sY;
    const f32x4* M14 = (const f32x4*)sM1;
    f32x4 acc = -M14[c * 32 + tx];
    for (int m = 0; m < 128; ++m)
        acc += sM1[c * 128 + m] * Y4[m * 32 + tx];
    const uint32_t lo = (uint32_t)f2bf(acc[0]) | ((uint32_t)f2bf(acc[1]) << 16);
    const uint32_t hi = (uint32_t)f2bf(acc[2]) | ((uint32_t)f2bf(acc[3]) << 16);
    const uint32_t byteoff = (uint32_t)((c * 256 + tx * 8) ^ ((c & 7) << 4));
    *(uint2*)(wsb + 32768 + byteoff) = make_uint2(lo, hi);
    if (blockIdx.x == 0 && tid == 0) {
        float trace = 0.0f;
        for (int i = 0; i < 16; ++i) trace += dbuf[132 + i];
        const float ldK = dbuf[128], ldG = dbuf[129];
        const float dof = (float)dofp[0];
        out[67649536] = -0.5f * dof * (-(ldG - ldK) + trace - 128.0f);
    }
}

// ---------------------------------------------------------------------------
// main: Gti = T*W, gt = tt + rowsum((T*Q) o T).
// PERSISTENT: 512 blocks (2/CU) x 512 thr; LDS image staged once; then a
// barrier-free tile loop (128 rows/tile, 16 rows/wave) with T-prefetch
// double-buffered through the t registers. VGPR target <=128 (2 blk/CU).
// ---------------------------------------------------------------------------
__global__ __launch_bounds__(512, 4) void main_kernel(
    const float* __restrict__ Kti, const float* __restrict__ Kt,
    const float* __restrict__ ws, float* __restrict__ Gti,
    float* __restrict__ gt, int ntiles)
{
    __shared__ __align__(16) char smem[65536];   // Wt|Qt bf16 swizzled image
    const int tid = threadIdx.x;
    const int lane = tid & 63, wid = tid >> 6;
    const int l15 = lane & 15, l4 = lane >> 4;
    const int wrow = wid * 16;                   // wave's row offset in tile

    {   // stage ws -> LDS once (L2/L3-hot)
        f32x4* s4 = (f32x4*)smem;
        const f32x4* w4 = (const f32x4*)ws;
        #pragma unroll
        for (int i = 0; i < 8; ++i) s4[tid + i * 512] = w4[tid + i * 512];
    }

    int tile = blockIdx.x;
    // preload tile 0: T[row = tile*128 + wrow + l15][l4*8 + kc*32 ..+8]
    f32x4 t[4][2];
    {
        const float* tb = Kti + ((size_t)tile * 128 + wrow + l15) * 128 + l4 * 8;
        #pragma unroll
        for (int kc = 0; kc < 4; ++kc) {
            t[kc][0] = *(const f32x4*)(tb + kc * 32);
            t[kc][1] = *(const f32x4*)(tb + kc * 32 + 4);
        }
    }
    __syncthreads();

    while (tile < ntiles) {
        const int curtile = tile;
        const int nexttile = tile + gridDim.x;

        // convert current T to bf16 A-frags (drains the in-flight loads)
        short8 a[4];
        #pragma unroll
        for (int kc = 0; kc < 4; ++kc) {
            a[kc] = { (short)f2bf(t[kc][0][0]), (short)f2bf(t[kc][0][1]),
                      (short)f2bf(t[kc][0][2]), (short)f2bf(t[kc][0][3]),
                      (short)f2bf(t[kc][1][0]), (short)f2bf(t[kc][1][1]),
                      (short)f2bf(t[kc][1][2]), (short)f2bf(t[kc][1][3]) };
        }

        // issue next tile's loads into the now-dead t regs (hidden under MFMA)
        if (nexttile < ntiles) {
            const float* tb = Kti + ((size_t)nexttile * 128 + wrow + l15) * 128 + l4 * 8;
            #pragma unroll
            for (int kc = 0; kc < 4; ++kc) {
                t[kc][0] = *(const f32x4*)(tb + kc * 32);
                t[kc][1] = *(const f32x4*)(tb + kc * 32 + 4);
            }
        }

        // 64-MFMA stream (B-frags from read-only LDS image)
        f32x4 accW[8] = {};
        f32x4 accZ[8] = {};
        #pragma unroll
        for (int kc = 0; kc < 4; ++kc) {
            const int k0 = kc * 32 + l4 * 8;
            #pragma unroll
            for (int ct = 0; ct < 8; ++ct) {
                const int c = ct * 16 + l15;
                const int byteoff = (c * 256 + k0 * 2) ^ ((c & 7) << 4);
                const short8 bW = *(const short8*)(smem + byteoff);
                const short8 bQ = *(const short8*)(smem + 32768 + byteoff);
                accW[ct] = __builtin_amdgcn_mfma_f32_16x16x32_bf16(a[kc], bW, accW[ct], 0, 0, 0);
                accZ[ct] = __builtin_amdgcn_mfma_f32_16x16x32_bf16(a[kc], bQ, accZ[ct], 0, 0, 0);
            }
        }

        // gt epilogue (C/D layout: col=l15, row=l4*4+r); trow re-reads L1/L2-hot
        #pragma unroll
        for (int r = 0; r < 4; ++r) {
            const int row = curtile * 128 + wrow + l4 * 4 + r;
            const float* trow = Kti + (size_t)row * 128;
            float p = 0.0f;
            #pragma unroll
            for (int ct = 0; ct < 8; ++ct) p += accZ[ct][r] * trow[ct * 16 + l15];
            p += __shfl_xor(p, 1, 64);
            p += __shfl_xor(p, 2, 64);
            p += __shfl_xor(p, 4, 64);
            p += __shfl_xor(p, 8, 64);
            if (l15 == 0) gt[row] = Kt[row] + p;
        }

        // Gti stores (16-lane / 64B coalesced granules)
        #pragma unroll
        for (int r = 0; r < 4; ++r) {
            float* grow = Gti + (size_t)(curtile * 128 + wrow + l4 * 4 + r) * 128 + l15;
            #pragma unroll
            for (int ct = 0; ct < 8; ++ct)
                grow[ct * 16] = accW[ct][r];
        }

        tile = nexttile;
    }
}

extern "C" void kernel_launch(void* const* d_in, const int* in_sizes, int n_in,
                              void* d_out, int out_size, void* d_ws, size_t ws_size,
                              hipStream_t stream)
{
    const float* Kii = (const float*)d_in[0];
    const float* Kti = (const float*)d_in[1];
    const float* Kt  = (const float*)d_in[2];
    const float* V   = (const float*)d_in[3];
    const float* gs  = (const float*)d_in[4];
    const int*   dof = (const int*)d_in[5];
    float* out = (float*)d_out;
    float* ws  = (float*)d_ws;

    const int N = in_sizes[2];          // 524288
    const int ntiles = N / 128;         // 4096

    k0_G<<<16, 256, 0, stream>>>(V, gs, out);
    k1_factor<<<1, 512, 0, stream>>>(Kii, out);
    k2_M1<<<16, 256, 0, stream>>>(out);
    k3_Y<<<16, 256, 0, stream>>>(out, (char*)ws);
    k4_Q<<<16, 256, 0, stream>>>(out, (char*)ws, dof);
    main_kernel<<<512, 512, 0, stream>>>(Kti, Kt, ws,
                                         out + 16384,          // Gti
                                         out + 67125248,       // gt
                                         ntiles);
}

// Round 6
// 321.636 us; speedup vs baseline: 2.7046x; 2.7046x over previous
//
#include <hip/hip_runtime.h>
#include <cstdint>

typedef __attribute__((ext_vector_type(8))) short short8;
typedef __attribute__((ext_vector_type(4))) float f32x4;

__device__ __forceinline__ unsigned short f2bf(float f) {
    uint32_t u = __builtin_bit_cast(uint32_t, f);
    u += 0x7FFFu + ((u >> 16) & 1u);   // round-to-nearest-even
    return (unsigned short)(u >> 16);
}

// out float offsets: Gii 0, Gti 16384, gt 67125248, obj 67649536
// fp32 scratch lives INSIDE the Gti region (overwritten later by main):
#define SG_OFF   16384     // G fp32 [128][128]
#define SM1_OFF  32768     // M1 = Kii^-1
#define SY_OFF   49152     // Y = G*M1
#define SX_OFF   65536     // X = Lunit^-1 (unit lower, upper zeros)
#define SD_OFF   81920     // d[0..127], [128]=logdetK, [129]=logdetG, [132+bid]=trace partials
// ws bytes [0,32768) = Wt bf16 swizzled; [32768,65536) = Qt bf16 swizzled
// swizzle: byte = (c*256 + k*2) ^ ((c&7)<<4)

// ---------------------------------------------------------------------------
// k0: G = V V^T /128 * e^s  -> out[0..16K) (Gii) and scratch sG. 16 blocks.
// ---------------------------------------------------------------------------
__global__ __launch_bounds__(256) void k0_G(
    const float* __restrict__ V, const float* __restrict__ gs,
    float* __restrict__ out)
{
    float* sG = out + SG_OFF;
    const float egs = expf(gs[0]) * (1.0f / 128.0f);
    const int ty = threadIdx.x >> 5, tx = threadIdx.x & 31;
    const int r = blockIdx.x * 8 + ty;
    const f32x4* V4 = (const f32x4*)V;
    f32x4 acc = {0.f, 0.f, 0.f, 0.f};
    for (int kq = 0; kq < 32; ++kq) {
        const f32x4 vr = V4[r * 32 + kq];
        #pragma unroll
        for (int e = 0; e < 4; ++e) {
            const f32x4 vc = V4[(tx * 4 + e) * 32 + kq];
            acc[e] += vr[0]*vc[0] + vr[1]*vc[1] + vr[2]*vc[2] + vr[3]*vc[3];
        }
    }
    acc *= egs;
    *(f32x4*)&out[r * 128 + tx * 4] = acc;
    *(f32x4*)&sG[r * 128 + tx * 4] = acc;
}

// ---------------------------------------------------------------------------
// k1: register-resident fused dual-LDL^T (K and G) + Gauss-Jordan X = L^-1.
// ---------------------------------------------------------------------------
__global__ __launch_bounds__(512) void k1_factor(
    const float* __restrict__ Kii, float* __restrict__ out)
{
    __shared__ float colA[2][128], colB[2][128], rowX[2][128];
    __shared__ float sDk[128], sDg[128], sRed[4];

    const int tid = threadIdx.x;
    const int ty = tid >> 5, tx = tid & 31;
    const int I0 = ty * 8, J0 = tx * 4;
    const float* sG = out + SG_OFF;
    float* sX = out + SX_OFF;
    float* dbuf = out + SD_OFF;

    f32x4 rA[8], rB[8], rX[8];
    #pragma unroll
    for (int r = 0; r < 8; ++r) {
        rA[r] = *(const f32x4*)&Kii[(size_t)(I0 + r) * 128 + J0];
        rB[r] = *(const f32x4*)&sG[(I0 + r) * 128 + J0];
        f32x4 z = {0.f, 0.f, 0.f, 0.f};
        #pragma unroll
        for (int e = 0; e < 4; ++e) z[e] = (I0 + r == J0 + e) ? 1.0f : 0.0f;
        rX[r] = z;
    }
    if (tx == 0) {
        #pragma unroll
        for (int r = 0; r < 8; ++r) { colA[0][I0 + r] = rA[r][0]; colB[0][I0 + r] = rB[r][0]; }
    }
    if (ty == 0) {
        #pragma unroll
        for (int e = 0; e < 4; ++e) rowX[0][J0 + e] = rX[0][e];
    }
    __syncthreads();

    for (int k = 0; k < 127; ++k) {
        const int b = k & 1;
        const float dK = colA[b][k], dG = colB[b][k];
        const float rdK = 1.0f / dK, rdG = 1.0f / dG;
        if (tid == 0) { sDk[k] = dK; sDg[k] = dG; }

        f32x4 caj = *(const f32x4*)&colA[b][J0];
        f32x4 cbj = *(const f32x4*)&colB[b][J0];
        const f32x4 xj = *(const f32x4*)&rowX[b][J0];
        #pragma unroll
        for (int e = 0; e < 4; ++e)
            if (J0 + e <= k) { caj[e] = 0.0f; cbj[e] = 0.0f; }

        f32x4 ca0 = *(const f32x4*)&colA[b][I0];
        f32x4 ca1 = *(const f32x4*)&colA[b][I0 + 4];
        f32x4 cb0 = *(const f32x4*)&colB[b][I0];
        f32x4 cb1 = *(const f32x4*)&colB[b][I0 + 4];
        #pragma unroll
        for (int r = 0; r < 4; ++r) {
            if (I0 + r <= k)     { ca0[r] = 0.0f; cb0[r] = 0.0f; }
            if (I0 + 4 + r <= k) { ca1[r] = 0.0f; cb1[r] = 0.0f; }
        }

        if (I0 + 7 > k) {
            #pragma unroll
            for (int r = 0; r < 8; ++r) {
                const float am = (r < 4) ? ca0[r & 3] : ca1[r & 3];
                const float bm = (r < 4) ? cb0[r & 3] : cb1[r & 3];
                const float fA = am * rdK;
                const float fB = bm * rdG;
                rA[r] -= fA * caj;
                rB[r] -= fB * cbj;
                rX[r] -= fA * xj;
            }
        }

        const int kn = k + 1, bn = kn & 1;
        if (tx == (kn >> 2)) {
            const int es = kn & 3;
            #pragma unroll
            for (int ee = 0; ee < 4; ++ee) if (ee == es) {
                #pragma unroll
                for (int r = 0; r < 8; ++r) {
                    colA[bn][I0 + r] = rA[r][ee];
                    colB[bn][I0 + r] = rB[r][ee];
                }
            }
        }
        if (ty == (kn >> 3)) {
            const int rs = kn & 7;
            #pragma unroll
            for (int rr = 0; rr < 8; ++rr) if (rr == rs) {
                #pragma unroll
                for (int e = 0; e < 4; ++e) rowX[bn][J0 + e] = rX[rr][e];
            }
        }
        __syncthreads();
    }
    if (tid == 511) { sDk[127] = rA[7][3]; sDg[127] = rB[7][3]; }

    #pragma unroll
    for (int r = 0; r < 8; ++r)
        *(f32x4*)&sX[(I0 + r) * 128 + J0] = rX[r];
    __syncthreads();

    if (tid < 128) {
        dbuf[tid] = sDk[tid];
        float lk = logf(sDk[tid]);
        float lg = logf(sDg[tid]);
        #pragma unroll
        for (int o = 32; o > 0; o >>= 1) { lk += __shfl_xor(lk, o, 64); lg += __shfl_xor(lg, o, 64); }
        if ((tid & 63) == 0) { sRed[(tid >> 6) * 2] = lk; sRed[(tid >> 6) * 2 + 1] = lg; }
    }
    __syncthreads();
    if (tid == 0) {
        dbuf[128] = sRed[0] + sRed[2];   // logdet K
        dbuf[129] = sRed[1] + sRed[3];   // logdet G
    }
}

// ---------------------------------------------------------------------------
// k2: M1 = X^T D^-1 X  (= Kii^-1). 16 blocks.
// ---------------------------------------------------------------------------
__global__ __launch_bounds__(256) void k2_M1(float* __restrict__ out)
{
    const float* sX = out + SX_OFF;
    const float* dbuf = out + SD_OFF;
    float* sM1 = out + SM1_OFF;
    __shared__ float srd[128];
    const int tid = threadIdx.x;
    if (tid < 128) srd[tid] = 1.0f / dbuf[tid];
    __syncthreads();
    const int ty = tid >> 5, tx = tid & 31;
    const int a = blockIdx.x * 8 + ty;
    const f32x4* X4 = (const f32x4*)sX;
    f32x4 acc = {0.f, 0.f, 0.f, 0.f};
    for (int k = a; k < 128; ++k) {          // X[k][a]=0 for k<a
        const float xa = sX[k * 128 + a] * srd[k];
        acc += xa * X4[k * 32 + tx];
    }
    *(f32x4*)&sM1[a * 128 + tx * 4] = acc;
}

// ---------------------------------------------------------------------------
// k3: Y = G*M1 -> scratch + Wt bf16 swizzled; trace partials. 16 blocks.
// ---------------------------------------------------------------------------
__global__ __launch_bounds__(256) void k3_Y(float* __restrict__ out, char* __restrict__ wsb)
{
    const float* sG = out + SG_OFF;
    const float* sM1 = out + SM1_OFF;
    float* sY = out + SY_OFF;
    float* dbuf = out + SD_OFF;
    const int tid = threadIdx.x;
    const int ty = tid >> 5, tx = tid & 31;
    const int c = blockIdx.x * 8 + ty;
    const f32x4* M14 = (const f32x4*)sM1;
    f32x4 acc = {0.f, 0.f, 0.f, 0.f};
    for (int m = 0; m < 128; ++m)
        acc += sG[c * 128 + m] * M14[m * 32 + tx];
    *(f32x4*)&sY[c * 128 + tx * 4] = acc;
    const uint32_t lo = (uint32_t)f2bf(acc[0]) | ((uint32_t)f2bf(acc[1]) << 16);
    const uint32_t hi = (uint32_t)f2bf(acc[2]) | ((uint32_t)f2bf(acc[3]) << 16);
    const uint32_t byteoff = (uint32_t)((c * 256 + tx * 8) ^ ((c & 7) << 4));
    *(uint2*)(wsb + byteoff) = make_uint2(lo, hi);
    float t;
    {
        const f32x4* G4 = (const f32x4*)sG;
        const int idx = blockIdx.x * 256 + tid;
        const f32x4 g = G4[idx], mm = M14[idx];
        t = g[0]*mm[0] + g[1]*mm[1] + g[2]*mm[2] + g[3]*mm[3];
    }
    #pragma unroll
    for (int o = 32; o > 0; o >>= 1) t += __shfl_xor(t, o, 64);
    __shared__ float sp[4];
    if ((tid & 63) == 0) sp[tid >> 6] = t;
    __syncthreads();
    if (tid == 0) dbuf[132 + blockIdx.x] = sp[0] + sp[1] + sp[2] + sp[3];
}

// ---------------------------------------------------------------------------
// k4: Q = M1*Y - M1 -> Qt bf16 swizzled; finalize obj. 16 blocks.
// ---------------------------------------------------------------------------
__global__ __launch_bounds__(256) void k4_Q(
    float* __restrict__ out, char* __restrict__ wsb, const int* __restrict__ dofp)
{
    const float* sM1 = out + SM1_OFF;
    const float* sY = out + SY_OFF;
    const float* dbuf = out + SD_OFF;
    const int tid = threadIdx.x;
    const int ty = tid >> 5, tx = tid & 31;
    const int c = blockIdx.x * 8 + ty;
    const f32x4* Y4 = (const f32x4*)sY;
    const f32x4* M14 = (const f32x4*)sM1;
    f32x4 acc = -M14[c * 32 + tx];
    for (int m = 0; m < 128; ++m)
        acc += sM1[c * 128 + m] * Y4[m * 32 + tx];
    const uint32_t lo = (uint32_t)f2bf(acc[0]) | ((uint32_t)f2bf(acc[1]) << 16);
    const uint32_t hi = (uint32_t)f2bf(acc[2]) | ((uint32_t)f2bf(acc[3]) << 16);
    const uint32_t byteoff = (uint32_t)((c * 256 + tx * 8) ^ ((c & 7) << 4));
    *(uint2*)(wsb + 32768 + byteoff) = make_uint2(lo, hi);
    if (blockIdx.x == 0 && tid == 0) {
        float trace = 0.0f;
        for (int i = 0; i < 16; ++i) trace += dbuf[132 + i];
        const float ldK = dbuf[128], ldG = dbuf[129];
        const float dof = (float)dofp[0];
        out[67649536] = -0.5f * dof * (-(ldG - ldK) + trace - 128.0f);
    }
}

// ---------------------------------------------------------------------------
// main: Gti = T*W, gt = tt + rowsum((T*Q) o T).
// 2048 blocks x 512 thr, 256 rows/block as TWO pipelined 128-row sub-tiles:
// cvt sub0 | issue sub1 loads | MFMA+epilogue+store sub0 | cvt sub1 | ...
// Keeps R4's locality (adjacent rows, short re-read distance); raises HBM
// duty by overlapping sub0 stores/epilogue with sub1 loads.
// ---------------------------------------------------------------------------
__global__ __launch_bounds__(512) void main_kernel(
    const float* __restrict__ Kti, const float* __restrict__ Kt,
    const float* __restrict__ ws, float* __restrict__ Gti,
    float* __restrict__ gt)
{
    __shared__ __align__(16) char smem[65536];   // Wt|Qt bf16 swizzled image
    const int tid = threadIdx.x;
    const int lane = tid & 63, wid = tid >> 6;
    const int l15 = lane & 15, l4 = lane >> 4;
    const int row0 = blockIdx.x * 256 + wid * 16;   // wave's 16 rows (sub-tile 0)

    // stage ws -> LDS (L2/L3-hot), 128 B/thread
    {
        f32x4* s4 = (f32x4*)smem;
        const f32x4* w4 = (const f32x4*)ws;
        #pragma unroll
        for (int i = 0; i < 8; ++i) s4[tid + i * 512] = w4[tid + i * 512];
    }

    // load sub-tile 0 (8 KB/wave in flight)
    f32x4 t[4][2];
    {
        const float* tb = Kti + (size_t)(row0 + l15) * 128 + l4 * 8;
        #pragma unroll
        for (int kc = 0; kc < 4; ++kc) {
            t[kc][0] = *(const f32x4*)(tb + kc * 32);
            t[kc][1] = *(const f32x4*)(tb + kc * 32 + 4);
        }
    }
    __syncthreads();

    #pragma unroll
    for (int s = 0; s < 2; ++s) {
        const int rowbase = row0 + s * 128;

        // cvt current sub-tile to bf16 A-frags (drains its loads)
        short8 a[4];
        #pragma unroll
        for (int kc = 0; kc < 4; ++kc) {
            a[kc] = { (short)f2bf(t[kc][0][0]), (short)f2bf(t[kc][0][1]),
                      (short)f2bf(t[kc][0][2]), (short)f2bf(t[kc][0][3]),
                      (short)f2bf(t[kc][1][0]), (short)f2bf(t[kc][1][1]),
                      (short)f2bf(t[kc][1][2]), (short)f2bf(t[kc][1][3]) };
        }

        // issue next sub-tile's loads into the now-dead t regs
        if (s == 0) {
            const float* tb = Kti + (size_t)(row0 + 128 + l15) * 128 + l4 * 8;
            #pragma unroll
            for (int kc = 0; kc < 4; ++kc) {
                t[kc][0] = *(const f32x4*)(tb + kc * 32);
                t[kc][1] = *(const f32x4*)(tb + kc * 32 + 4);
            }
        }

        // 64+64 MFMA stream (B-frags from read-only LDS image)
        f32x4 accW[8] = {};
        f32x4 accZ[8] = {};
        #pragma unroll
        for (int kc = 0; kc < 4; ++kc) {
            const int k0 = kc * 32 + l4 * 8;
            #pragma unroll
            for (int ct = 0; ct < 8; ++ct) {
                const int c = ct * 16 + l15;
                const int byteoff = (c * 256 + k0 * 2) ^ ((c & 7) << 4);
                const short8 bW = *(const short8*)(smem + byteoff);
                const short8 bQ = *(const short8*)(smem + 32768 + byteoff);
                accW[ct] = __builtin_amdgcn_mfma_f32_16x16x32_bf16(a[kc], bW, accW[ct], 0, 0, 0);
                accZ[ct] = __builtin_amdgcn_mfma_f32_16x16x32_bf16(a[kc], bQ, accZ[ct], 0, 0, 0);
            }
        }

        // gt epilogue (C/D layout: col=l15, row=l4*4+r); trow re-reads L1/L3-hot
        #pragma unroll
        for (int r = 0; r < 4; ++r) {
            const int row = rowbase + l4 * 4 + r;
            const float* trow = Kti + (size_t)row * 128;
            float p = 0.0f;
            #pragma unroll
            for (int ct = 0; ct < 8; ++ct) p += accZ[ct][r] * trow[ct * 16 + l15];
            p += __shfl_xor(p, 1, 64);
            p += __shfl_xor(p, 2, 64);
            p += __shfl_xor(p, 4, 64);
            p += __shfl_xor(p, 8, 64);
            if (l15 == 0) gt[row] = Kt[row] + p;
        }

        // Gti stores (16-lane / 64B coalesced granules), drain under next MFMA
        #pragma unroll
        for (int r = 0; r < 4; ++r) {
            float* grow = Gti + (size_t)(rowbase + l4 * 4 + r) * 128 + l15;
            #pragma unroll
            for (int ct = 0; ct < 8; ++ct)
                grow[ct * 16] = accW[ct][r];
        }
    }
}

extern "C" void kernel_launch(void* const* d_in, const int* in_sizes, int n_in,
                              void* d_out, int out_size, void* d_ws, size_t ws_size,
                              hipStream_t stream)
{
    const float* Kii = (const float*)d_in[0];
    const float* Kti = (const float*)d_in[1];
    const float* Kt  = (const float*)d_in[2];
    const float* V   = (const float*)d_in[3];
    const float* gs  = (const float*)d_in[4];
    const int*   dof = (const int*)d_in[5];
    float* out = (float*)d_out;
    float* ws  = (float*)d_ws;

    const int N = in_sizes[2];          // 524288
    const int nblocks = N / 256;        // 2048

    k0_G<<<16, 256, 0, stream>>>(V, gs, out);
    k1_factor<<<1, 512, 0, stream>>>(Kii, out);
    k2_M1<<<16, 256, 0, stream>>>(out);
    k3_Y<<<16, 256, 0, stream>>>(out, (char*)ws);
    k4_Q<<<16, 256, 0, stream>>>(out, (char*)ws, dof);
    main_kernel<<<nblocks, 512, 0, stream>>>(Kti, Kt, ws,
                                             out + 16384,          // Gti
                                             out + 67125248);      // gt
}